// Round 3
// baseline (590.752 us; speedup 1.0000x reference)
//
#include <hip/hip_runtime.h>
#include <stdint.h>
#include <stddef.h>

typedef float f32x4 __attribute__((ext_vector_type(4)));
typedef short bf16x8 __attribute__((ext_vector_type(8)));
typedef unsigned short u16;
typedef u16 u16x4 __attribute__((ext_vector_type(4)));
typedef u16 u16x8 __attribute__((ext_vector_type(8)));

#define MFMA16(a,b,c) __builtin_amdgcn_mfma_f32_16x16x32_bf16((a),(b),(c),0,0,0)

__device__ __forceinline__ float bf2f(u16 u){ union{unsigned int i;float f;}v; v.i=((unsigned int)u)<<16; return v.f; }
__device__ __forceinline__ u16 f2bf(float f){ union{float f;unsigned int i;}v; v.f=f; unsigned int x=v.i; return (u16)((x + 0x7FFFu + ((x>>16)&1u))>>16); }

__device__ __forceinline__ void gload_lds16(const void* g, void* l){
  __builtin_amdgcn_global_load_lds((const __attribute__((address_space(1))) void*)g,
                                   (__attribute__((address_space(3))) void*)l, 16, 0, 0);
}

// ---------------- elementwise ----------------
__global__ void k_convert(const float* __restrict__ src, u16* __restrict__ dst, int n4){
  int stride = gridDim.x * blockDim.x;
  for (int i = blockIdx.x*blockDim.x + threadIdx.x; i < n4; i += stride){
    float4 v = ((const float4*)src)[i];
    u16x4 o; o[0]=f2bf(v.x); o[1]=f2bf(v.y); o[2]=f2bf(v.z); o[3]=f2bf(v.w);
    ((u16x4*)dst)[i] = o;
  }
}

__global__ void k_rope_table(float* __restrict__ ct, float* __restrict__ st){
  int i = blockIdx.x*blockDim.x + threadIdx.x; // 4096*64 exactly
  int s = i >> 6, p = i & 63;
  float freq = 1.0f / powf(10000.0f, (float)(2*p) * (1.0f/128.0f));
  float ang = (float)s * freq;
  ct[i] = cosf(ang); st[i] = sinf(ang);
}

// in-place RoPE on bf16 [rows x cols], cols8 = cols/8, position = row % 4096
__global__ void k_rope_apply(u16* __restrict__ t, const float* __restrict__ ct,
                             const float* __restrict__ st, int cols8, int n){
  int stride = gridDim.x * blockDim.x;
  for (int i = blockIdx.x*blockDim.x + threadIdx.x; i < n; i += stride){
    int row = i / cols8, rem = i - row*cols8;
    int s = row & 4095;
    int d0 = (rem*8) & 127;
    int p0 = d0 >> 1;
    const float4 c  = *(const float4*)(ct + s*64 + p0);
    const float4 sn = *(const float4*)(st + s*64 + p0);
    u16x8 v = ((const u16x8*)t)[i];
    u16x8 o;
    float x1, x2;
    x1=bf2f(v[0]); x2=bf2f(v[1]); o[0]=f2bf(x1*c.x-x2*sn.x); o[1]=f2bf(x1*sn.x+x2*c.x);
    x1=bf2f(v[2]); x2=bf2f(v[3]); o[2]=f2bf(x1*c.y-x2*sn.y); o[3]=f2bf(x1*sn.y+x2*c.y);
    x1=bf2f(v[4]); x2=bf2f(v[5]); o[4]=f2bf(x1*c.z-x2*sn.z); o[5]=f2bf(x1*sn.z+x2*c.z);
    x1=bf2f(v[6]); x2=bf2f(v[7]); o[6]=f2bf(x1*c.w-x2*sn.w); o[7]=f2bf(x1*sn.w+x2*c.w);
    ((u16x8*)t)[i] = o;
  }
}

// ---------------- GEMM: C[M,N] = A[M,K] @ Bt[N,K]^T (bf16 in, f32 acc) ----------------
__device__ __forceinline__ void gemm_stage(const u16* __restrict__ G, u16* lds,
                                           int base_row, int K, int k0, int wid, int lane){
  #pragma unroll
  for (int j2 = 0; j2 < 2; ++j2){
    int j = wid*2 + j2;
    int row = j*16 + (lane >> 2);
    int c16 = (lane & 3) ^ ((row >> 1) & 3);
    gload_lds16(G + (size_t)(base_row + row)*K + k0 + c16*8, lds + j*512);
  }
}

template<int EPI>
__global__ __launch_bounds__(256) void k_gemm_bt(
    const u16* __restrict__ A, const u16* __restrict__ Bt,
    float* __restrict__ Cf,
    u16* __restrict__ qb, u16* __restrict__ kb, u16* __restrict__ vtb,
    int M, int N, int K)
{
  __shared__ u16 As[2][4096];
  __shared__ u16 Bs[2][4096];
  const int tid = threadIdx.x, wid = tid >> 6, lane = tid & 63;
  const int lr = lane & 15, lg = lane >> 4;
  const int wr = wid >> 1, wc = wid & 1;
  const int bm = blockIdx.x * 128, bn = blockIdx.y * 128;
  const int nsteps = K >> 5;

  f32x4 acc[4][4] = {};

  gemm_stage(A,  As[0], bm, K, 0, wid, lane);
  gemm_stage(Bt, Bs[0], bn, K, 0, wid, lane);
  __syncthreads();
  int buf = 0;
  for (int t = 0; t < nsteps; ++t){
    if (t + 1 < nsteps){
      gemm_stage(A,  As[buf^1], bm, K, (t+1)<<5, wid, lane);
      gemm_stage(Bt, Bs[buf^1], bn, K, (t+1)<<5, wid, lane);
    }
    bf16x8 af[4], bfv[4];
    #pragma unroll
    for (int i = 0; i < 4; ++i){
      int ar = wr*64 + i*16 + lr;
      af[i]  = *(const bf16x8*)&As[buf][ar*32 + ((lg ^ ((ar>>1)&3)))*8];
      int br = wc*64 + i*16 + lr;
      bfv[i] = *(const bf16x8*)&Bs[buf][br*32 + ((lg ^ ((br>>1)&3)))*8];
    }
    #pragma unroll
    for (int i = 0; i < 4; ++i)
      #pragma unroll
      for (int j = 0; j < 4; ++j)
        acc[i][j] = MFMA16(af[i], bfv[j], acc[i][j]);
    __syncthreads();
    buf ^= 1;
  }

  #pragma unroll
  for (int i = 0; i < 4; ++i){
    int mrow = bm + wr*64 + i*16 + lg*4;
    #pragma unroll
    for (int j = 0; j < 4; ++j){
      int ncol = bn + wc*64 + j*16 + lr;
      f32x4 v = acc[i][j];
      if (EPI == 0){
        #pragma unroll
        for (int r = 0; r < 4; ++r)
          Cf[(size_t)(mrow + r)*N + ncol] = v[r];
      } else {
        if (ncol < 2048){
          #pragma unroll
          for (int r = 0; r < 4; ++r) qb[(size_t)(mrow + r)*2048 + ncol] = f2bf(v[r]);
        } else if (ncol < 2560){
          #pragma unroll
          for (int r = 0; r < 4; ++r) kb[(size_t)(mrow + r)*512 + (ncol - 2048)] = f2bf(v[r]);
        } else {
          int np = ncol - 2560, hkk = np >> 7, d = np & 127;
          int bb2 = mrow >> 12, sl = mrow & 4095;
          u16x4 pk;
          #pragma unroll
          for (int r = 0; r < 4; ++r) pk[r] = f2bf(v[r]);
          *(u16x4*)(vtb + ((size_t)((bb2*4 + hkk)*128 + d))*4096 + sl) = pk;
        }
      }
    }
  }
}

// ---------------- attention: 8 waves x 32 q-rows = 256 rows/block ----------------
// K/V staged once per block in LDS (global_load_lds, inverse-XOR-swizzled source).
// grid 512: bid -> qblk(4b) | h(4b) | b(1b), XCD-swizzled so each XCD owns one (b,hk) panel.
__global__ __launch_bounds__(512, 4) void k_attn(
    const u16* __restrict__ qb, const u16* __restrict__ kb,
    const u16* __restrict__ vtb, u16* __restrict__ ob)
{
  __shared__ u16 Ks[64*128];    // [key 64][dim 128], 16B-chunk XOR(row&7) swizzle
  __shared__ u16 Vs[128*64];    // [dim 128][key 64], 16B-chunk XOR(row&7) swizzle
  __shared__ u16 Ps[8][32*64];  // per-wave P: [qrow 32][key 64], XOR(row&7) swizzle

  const int bid0 = blockIdx.x;
  const int bid = (bid0 & 7)*64 + (bid0 >> 3);      // bijective XCD swizzle (512 = 8*64)
  const int qblk = bid & 15, h = (bid >> 4) & 15, b = bid >> 8;
  const int hk = h >> 2;
  const int tid = threadIdx.x, wid = tid >> 6, lane = tid & 63;
  const int lr = lane & 15, lg = lane >> 4;
  const int q0 = qblk*256;
  const int qw = q0 + wid*32;

  // Q fragments: rows qw+mt*16+lr, dims ks*32+lg*8 (B-operand of swapped QK^T)
  bf16x8 qf[2][4];
  #pragma unroll
  for (int mt = 0; mt < 2; ++mt){
    const u16* qp = qb + (size_t)(b*4096 + qw + mt*16 + lr)*2048 + h*128;
    #pragma unroll
    for (int ks = 0; ks < 4; ++ks)
      qf[mt][ks] = *(const bf16x8*)(qp + ks*32 + lg*8);
  }

  // staging slots: thread handles K slots sA,sA+512 and V slots sA,sA+512 (16B each)
  const int sA = wid*64 + lane;
  const int krA = sA >> 4, kcA = sA & 15;
  const int krB = krA + 32;
  const int vrA = sA >> 3, vcA = sA & 7;
  const int vrB = vrA + 64;
  const u16* kSrcA = kb + (size_t)(b*4096 + krA)*512 + hk*128 + ((kcA ^ (krA & 7))*8);
  const u16* kSrcB = kb + (size_t)(b*4096 + krB)*512 + hk*128 + ((kcA ^ (krB & 7))*8);
  const u16* vSrcA = vtb + ((size_t)(b*4 + hk)*128 + vrA)*4096 + ((vcA ^ (vrA & 7))*8);
  const u16* vSrcB = vtb + ((size_t)(b*4 + hk)*128 + vrB)*4096 + ((vcA ^ (vrB & 7))*8);
  u16* const ldsKA = Ks + sA*8;
  u16* const ldsKB = Ks + (sA + 512)*8;
  u16* const ldsVA = Vs + sA*8;
  u16* const ldsVB = Vs + (sA + 512)*8;

  u16* Pw = (u16*)Ps[wid];

  f32x4 o[2][8] = {};
  float lst[2] = {0.f, 0.f};

  const int kt0 = (q0 >= 512) ? (q0 - 512) : 0;
  const int ktend = q0 + 256;

  for (int kt = kt0; kt < ktend; kt += 64){
    __syncthreads();   // previous tile fully consumed
    gload_lds16(kSrcA + (size_t)kt*512, ldsKA);
    gload_lds16(kSrcB + (size_t)kt*512, ldsKB);
    gload_lds16(vSrcA + kt, ldsVA);
    gload_lds16(vSrcB + kt, ldsVB);
    __syncthreads();   // staging drained (vmcnt0 at barrier)

    if (kt + 63 < qw - 512 || kt > qw + 31) continue;  // fully masked for this wave

    // swapped QK^T: sc[mt][nt]: row = key (lg*4+r within nt*16), col = q (lr)
    f32x4 sc[2][4] = {};
    #pragma unroll
    for (int ks = 0; ks < 4; ++ks){
      #pragma unroll
      for (int nt = 0; nt < 4; ++nt){
        int krow = nt*16 + lr;
        bf16x8 kf = *(const bf16x8*)&Ks[krow*128 + (((ks*4 + lg) ^ (krow & 7)))*8];
        sc[0][nt] = MFMA16(kf, qf[0][ks], sc[0][nt]);
        sc[1][nt] = MFMA16(kf, qf[1][ks], sc[1][nt]);
      }
    }

    // softcap + fixed-max softmax: p = exp2(28.85*(tanh(a)-1)), tanh via odd poly
    #pragma unroll
    for (int mt = 0; mt < 2; ++mt){
      int dql = (qw + mt*16 + lr) - kt - lg*4;
      float ps = 0.f;
      #pragma unroll
      for (int nt = 0; nt < 4; ++nt){
        unsigned int pk[2];
        #pragma unroll
        for (int j = 0; j < 2; ++j){
          unsigned int w2[2];
          #pragma unroll
          for (int rr = 0; rr < 2; ++rr){
            const int r = j*2 + rr;
            float a = sc[mt][nt][r] * 0.00441941738f;   // s/(20*sqrt(128))
            a = fminf(fmaxf(a, -0.55f), 0.55f);
            float a2 = a*a;
            float hp = __builtin_fmaf(a2, 0.13333333f, -0.33333333f);
            hp = __builtin_fmaf(a2, hp, 1.0f);
            float t = a * hp;
            float g = (t - 1.0f) * 28.853901f;
            float p = __builtin_amdgcn_exp2f(g);
            int diff = dql - (nt*16 + r);
            p = ((unsigned)diff <= 512u) ? p : 0.f;
            ps += p;
            union{float f; unsigned int u;} cv; cv.f = p;
            w2[rr] = cv.u + 0x8000u;
          }
          pk[j] = (w2[0] >> 16) | (w2[1] & 0xffff0000u);
        }
        const int row = mt*16 + lr;
        const int bytecol = nt*32 + lg*8;
        const int c16 = bytecol >> 4;
        char* basep = (char*)Pw + row*128 + (((c16 ^ (row & 7)) << 4)) + (bytecol & 15);
        *(unsigned int*)(basep)     = pk[0];
        *(unsigned int*)(basep + 4) = pk[1];
      }
      lst[mt] += ps;
    }

    __builtin_amdgcn_s_waitcnt(0xC07F);     // lgkmcnt(0): this wave's P writes done
    __builtin_amdgcn_sched_barrier(0);

    // PV: o[q][d] += P[q][key] * Vt[d][key]
    #pragma unroll
    for (int kk = 0; kk < 2; ++kk){
      bf16x8 pa0 = *(const bf16x8*)((char*)Pw + (lr)*128    + (((kk*4+lg) ^ (lr & 7)) << 4));
      bf16x8 pa1 = *(const bf16x8*)((char*)Pw + (16+lr)*128 + (((kk*4+lg) ^ (lr & 7)) << 4));
      #pragma unroll
      for (int dt = 0; dt < 8; ++dt){
        int vrow = dt*16 + lr;
        bf16x8 vf = *(const bf16x8*)&Vs[vrow*64 + (((kk*4 + lg) ^ (lr & 7)))*8];
        o[0][dt] = MFMA16(pa0, vf, o[0][dt]);
        o[1][dt] = MFMA16(pa1, vf, o[1][dt]);
      }
    }
  }

  // finalize: sum l across lg groups, normalize, store
  #pragma unroll
  for (int mt = 0; mt < 2; ++mt){
    lst[mt] += __shfl_xor(lst[mt], 16);
    lst[mt] += __shfl_xor(lst[mt], 32);
  }
  #pragma unroll
  for (int mt = 0; mt < 2; ++mt){
    #pragma unroll
    for (int r = 0; r < 4; ++r){
      float l = __shfl(lst[mt], lg*4 + r);
      float inv = 1.0f / l;
      int qg = qw + mt*16 + lg*4 + r;
      u16* op = ob + (size_t)(b*4096 + qg)*2048 + h*128;
      #pragma unroll
      for (int dt = 0; dt < 8; ++dt)
        op[dt*16 + lr] = f2bf(o[mt][dt][r] * inv);
    }
  }
}

// ---------------- launch ----------------
extern "C" void kernel_launch(void* const* d_in, const int* in_sizes, int n_in,
                              void* d_out, int out_size, void* d_ws, size_t ws_size,
                              hipStream_t stream)
{
  const float* x  = (const float*)d_in[0];
  const float* wq = (const float*)d_in[1];
  const float* wk = (const float*)d_in[2];
  const float* wv = (const float*)d_in[3];
  const float* wo = (const float*)d_in[4];
  float* outp = (float*)d_out;
  char* ws = (char*)d_ws;

  u16* xb    = (u16*)(ws);                  // bf16 x; reused as attn out
  u16* ob    = xb;
  u16* qbuf  = (u16*)(ws + 33554432u);
  u16* kbuf  = (u16*)(ws + 67108864u);
  u16* vtb   = (u16*)(ws + 75497472u);
  u16* wqkvb = (u16*)(ws + 83886080u);
  u16* wob   = (u16*)(ws + 96468992u);
  float* ct  = (float*)(ws + 104857600u);
  float* st  = (float*)(ws + 105906176u);

  k_convert<<<2048, 256, 0, stream>>>(x,  xb,            4194304);
  k_convert<<<2048, 256, 0, stream>>>(wq, wqkvb,         1048576);
  k_convert<<<1024, 256, 0, stream>>>(wk, wqkvb+4194304,  262144);
  k_convert<<<1024, 256, 0, stream>>>(wv, wqkvb+5242880,  262144);
  k_convert<<<2048, 256, 0, stream>>>(wo, wob,           1048576);
  k_rope_table<<<1024, 256, 0, stream>>>(ct, st);

  dim3 g1(8192/128, 3072/128);
  k_gemm_bt<1><<<g1, 256, 0, stream>>>(xb, wqkvb, nullptr, qbuf, kbuf, vtb, 8192, 3072, 2048);

  k_rope_apply<<<2048, 256, 0, stream>>>(qbuf, ct, st, 256, 8192*256);
  k_rope_apply<<<2048, 256, 0, stream>>>(kbuf, ct, st, 64,  8192*64);

  k_attn<<<512, 512, 0, stream>>>(qbuf, kbuf, vtb, ob);

  dim3 g2(8192/128, 2048/128);
  k_gemm_bt<0><<<g2, 256, 0, stream>>>(ob, wob, outp, nullptr, nullptr, nullptr, 8192, 2048, 2048);
}

// Round 4
// 439.702 us; speedup vs baseline: 1.3435x; 1.3435x over previous
//
#include <hip/hip_runtime.h>
#include <stdint.h>
#include <stddef.h>

typedef float f32x4 __attribute__((ext_vector_type(4)));
typedef short bf16x8 __attribute__((ext_vector_type(8)));
typedef unsigned short u16;
typedef u16 u16x4 __attribute__((ext_vector_type(4)));
typedef u16 u16x8 __attribute__((ext_vector_type(8)));

#define MFMA16(a,b,c) __builtin_amdgcn_mfma_f32_16x16x32_bf16((a),(b),(c),0,0,0)

__device__ __forceinline__ float bf2f(u16 u){ union{unsigned int i;float f;}v; v.i=((unsigned int)u)<<16; return v.f; }
__device__ __forceinline__ u16 f2bf(float f){ union{float f;unsigned int i;}v; v.f=f; unsigned int x=v.i; return (u16)((x + 0x7FFFu + ((x>>16)&1u))>>16); }

__device__ __forceinline__ void gload_lds16(const void* g, void* l){
  __builtin_amdgcn_global_load_lds((const __attribute__((address_space(1))) void*)g,
                                   (__attribute__((address_space(3))) void*)l, 16, 0, 0);
}

// ---------------- elementwise ----------------
__global__ void k_convert(const float* __restrict__ src, u16* __restrict__ dst, int n4){
  int stride = gridDim.x * blockDim.x;
  for (int i = blockIdx.x*blockDim.x + threadIdx.x; i < n4; i += stride){
    float4 v = ((const float4*)src)[i];
    u16x4 o; o[0]=f2bf(v.x); o[1]=f2bf(v.y); o[2]=f2bf(v.z); o[3]=f2bf(v.w);
    ((u16x4*)dst)[i] = o;
  }
}

__global__ void k_rope_table(float* __restrict__ ct, float* __restrict__ st){
  int i = blockIdx.x*blockDim.x + threadIdx.x; // 4096*64 exactly
  int s = i >> 6, p = i & 63;
  float freq = 1.0f / powf(10000.0f, (float)(2*p) * (1.0f/128.0f));
  float ang = (float)s * freq;
  ct[i] = cosf(ang); st[i] = sinf(ang);
}

// in-place RoPE on bf16 [rows x cols], cols8 = cols/8, position = row % 4096
__global__ void k_rope_apply(u16* __restrict__ t, const float* __restrict__ ct,
                             const float* __restrict__ st, int cols8, int n){
  int stride = gridDim.x * blockDim.x;
  for (int i = blockIdx.x*blockDim.x + threadIdx.x; i < n; i += stride){
    int row = i / cols8, rem = i - row*cols8;
    int s = row & 4095;
    int d0 = (rem*8) & 127;
    int p0 = d0 >> 1;
    const float4 c  = *(const float4*)(ct + s*64 + p0);
    const float4 sn = *(const float4*)(st + s*64 + p0);
    u16x8 v = ((const u16x8*)t)[i];
    u16x8 o;
    float x1, x2;
    x1=bf2f(v[0]); x2=bf2f(v[1]); o[0]=f2bf(x1*c.x-x2*sn.x); o[1]=f2bf(x1*sn.x+x2*c.x);
    x1=bf2f(v[2]); x2=bf2f(v[3]); o[2]=f2bf(x1*c.y-x2*sn.y); o[3]=f2bf(x1*sn.y+x2*c.y);
    x1=bf2f(v[4]); x2=bf2f(v[5]); o[4]=f2bf(x1*c.z-x2*sn.z); o[5]=f2bf(x1*sn.z+x2*c.z);
    x1=bf2f(v[6]); x2=bf2f(v[7]); o[6]=f2bf(x1*c.w-x2*sn.w); o[7]=f2bf(x1*sn.w+x2*c.w);
    ((u16x8*)t)[i] = o;
  }
}

// ---------------- GEMM: C[M,N] = A[M,K] @ Bt[N,K]^T (bf16 in, f32 acc) ----------------
__device__ __forceinline__ void gemm_stage(const u16* __restrict__ G, u16* lds,
                                           int base_row, int K, int k0, int wid, int lane){
  #pragma unroll
  for (int j2 = 0; j2 < 2; ++j2){
    int j = wid*2 + j2;
    int row = j*16 + (lane >> 2);
    int c16 = (lane & 3) ^ ((row >> 1) & 3);
    gload_lds16(G + (size_t)(base_row + row)*K + k0 + c16*8, lds + j*512);
  }
}

template<int EPI>
__global__ __launch_bounds__(256) void k_gemm_bt(
    const u16* __restrict__ A, const u16* __restrict__ Bt,
    float* __restrict__ Cf,
    u16* __restrict__ qb, u16* __restrict__ kb, u16* __restrict__ vtb,
    int M, int N, int K)
{
  __shared__ u16 As[2][4096];
  __shared__ u16 Bs[2][4096];
  const int tid = threadIdx.x, wid = tid >> 6, lane = tid & 63;
  const int lr = lane & 15, lg = lane >> 4;
  const int wr = wid >> 1, wc = wid & 1;
  const int bm = blockIdx.x * 128, bn = blockIdx.y * 128;
  const int nsteps = K >> 5;

  f32x4 acc[4][4] = {};

  gemm_stage(A,  As[0], bm, K, 0, wid, lane);
  gemm_stage(Bt, Bs[0], bn, K, 0, wid, lane);
  __syncthreads();
  int buf = 0;
  for (int t = 0; t < nsteps; ++t){
    if (t + 1 < nsteps){
      gemm_stage(A,  As[buf^1], bm, K, (t+1)<<5, wid, lane);
      gemm_stage(Bt, Bs[buf^1], bn, K, (t+1)<<5, wid, lane);
    }
    bf16x8 af[4], bfv[4];
    #pragma unroll
    for (int i = 0; i < 4; ++i){
      int ar = wr*64 + i*16 + lr;
      af[i]  = *(const bf16x8*)&As[buf][ar*32 + ((lg ^ ((ar>>1)&3)))*8];
      int br = wc*64 + i*16 + lr;
      bfv[i] = *(const bf16x8*)&Bs[buf][br*32 + ((lg ^ ((br>>1)&3)))*8];
    }
    #pragma unroll
    for (int i = 0; i < 4; ++i)
      #pragma unroll
      for (int j = 0; j < 4; ++j)
        acc[i][j] = MFMA16(af[i], bfv[j], acc[i][j]);
    __syncthreads();
    buf ^= 1;
  }

  #pragma unroll
  for (int i = 0; i < 4; ++i){
    int mrow = bm + wr*64 + i*16 + lg*4;
    #pragma unroll
    for (int j = 0; j < 4; ++j){
      int ncol = bn + wc*64 + j*16 + lr;
      f32x4 v = acc[i][j];
      if (EPI == 0){
        #pragma unroll
        for (int r = 0; r < 4; ++r)
          Cf[(size_t)(mrow + r)*N + ncol] = v[r];
      } else {
        if (ncol < 2048){
          #pragma unroll
          for (int r = 0; r < 4; ++r) qb[(size_t)(mrow + r)*2048 + ncol] = f2bf(v[r]);
        } else if (ncol < 2560){
          #pragma unroll
          for (int r = 0; r < 4; ++r) kb[(size_t)(mrow + r)*512 + (ncol - 2048)] = f2bf(v[r]);
        } else {
          int np = ncol - 2560, hkk = np >> 7, d = np & 127;
          int bb2 = mrow >> 12, sl = mrow & 4095;
          u16x4 pk;
          #pragma unroll
          for (int r = 0; r < 4; ++r) pk[r] = f2bf(v[r]);
          *(u16x4*)(vtb + ((size_t)((bb2*4 + hkk)*128 + d))*4096 + sl) = pk;
        }
      }
    }
  }
}

// ---------------- attention: 8 waves x 16 q-rows = 128 rows/block ----------------
// K/V staged once per block in LDS; per-thread state sized to fit 128-VGPR cap (no spill).
// grid 1024: bid -> qblk(5b) | h(4b) | b(1b); XCD swizzle gives each XCD one (b,hk) panel.
__global__ __launch_bounds__(512, 4) void k_attn(
    const u16* __restrict__ qb, const u16* __restrict__ kb,
    const u16* __restrict__ vtb, u16* __restrict__ ob)
{
  __shared__ u16 Ks[64*128];    // [key 64][dim 128], 16B-chunk XOR(row&7) swizzle
  __shared__ u16 Vs[128*64];    // [dim 128][key 64], 16B-chunk XOR(row&7) swizzle
  __shared__ u16 Ps[8][16*64];  // per-wave P: [qrow 16][key 64], XOR(row&7) swizzle

  const int bid0 = blockIdx.x;
  const int bid = (bid0 & 7)*128 + (bid0 >> 3);     // bijective XCD swizzle (1024 = 8*128)
  const int qblk = bid & 31, h = (bid >> 5) & 15, b = bid >> 9;
  const int hk = h >> 2;
  const int tid = threadIdx.x, wid = tid >> 6, lane = tid & 63;
  const int lr = lane & 15, lg = lane >> 4;
  const int q0 = qblk*128;
  const int qw = q0 + wid*16;

  // Q fragments: rows qw+lr, dims ks*32+lg*8 (B-operand of swapped QK^T)
  bf16x8 qf[4];
  {
    const u16* qp = qb + (size_t)(b*4096 + qw + lr)*2048 + h*128;
    #pragma unroll
    for (int ks = 0; ks < 4; ++ks)
      qf[ks] = *(const bf16x8*)(qp + ks*32 + lg*8);
  }

  // staging slots: thread handles K slots sA,sA+512 and V slots sA,sA+512 (16B each)
  const int sA = wid*64 + lane;
  const int krA = sA >> 4, kcA = sA & 15;
  const int krB = krA + 32;
  const int vrA = sA >> 3, vcA = sA & 7;
  const int vrB = vrA + 64;
  const u16* kSrcA = kb + (size_t)(b*4096 + krA)*512 + hk*128 + ((kcA ^ (krA & 7))*8);
  const u16* kSrcB = kb + (size_t)(b*4096 + krB)*512 + hk*128 + ((kcA ^ (krB & 7))*8);
  const u16* vSrcA = vtb + ((size_t)(b*4 + hk)*128 + vrA)*4096 + ((vcA ^ (vrA & 7))*8);
  const u16* vSrcB = vtb + ((size_t)(b*4 + hk)*128 + vrB)*4096 + ((vcA ^ (vrB & 7))*8);
  u16* const ldsKA = Ks + sA*8;
  u16* const ldsKB = Ks + (sA + 512)*8;
  u16* const ldsVA = Vs + sA*8;
  u16* const ldsVB = Vs + (sA + 512)*8;

  u16* Pw = (u16*)Ps[wid];

  f32x4 o[8] = {};
  float lst = 0.f;

  const int kt0 = (q0 >= 512) ? (q0 - 512) : 0;
  const int ktend = q0 + 128;

  for (int kt = kt0; kt < ktend; kt += 64){
    __syncthreads();   // previous tile fully consumed
    gload_lds16(kSrcA + (size_t)kt*512, ldsKA);
    gload_lds16(kSrcB + (size_t)kt*512, ldsKB);
    gload_lds16(vSrcA + kt, ldsVA);
    gload_lds16(vSrcB + kt, ldsVB);
    __syncthreads();   // staging drained (vmcnt0 at barrier)

    if (kt > qw + 15 || kt + 63 < qw - 512) continue;  // fully masked for this wave

    // swapped QK^T: sc[nt]: row = key (lg*4+r within nt*16), col = q (lr)
    f32x4 sc[4] = {};
    #pragma unroll
    for (int ks = 0; ks < 4; ++ks){
      #pragma unroll
      for (int nt = 0; nt < 4; ++nt){
        int krow = nt*16 + lr;
        bf16x8 kf = *(const bf16x8*)&Ks[krow*128 + (((ks*4 + lg) ^ (krow & 7)))*8];
        sc[nt] = MFMA16(kf, qf[ks], sc[nt]);
      }
    }

    // softcap + fixed-max softmax: p = exp2(28.85*(tanh(a)-1)), tanh via odd poly
    {
      int dql = (qw + lr) - kt - lg*4;   // qg - key base of this lane
      float ps = 0.f;
      #pragma unroll
      for (int nt = 0; nt < 4; ++nt){
        unsigned int pk[2];
        #pragma unroll
        for (int j = 0; j < 2; ++j){
          unsigned int w2[2];
          #pragma unroll
          for (int rr = 0; rr < 2; ++rr){
            const int r = j*2 + rr;
            float a = sc[nt][r] * 0.00441941738f;   // s/(20*sqrt(128))
            a = fminf(fmaxf(a, -0.55f), 0.55f);
            float a2 = a*a;
            float hp = __builtin_fmaf(a2, 0.13333333f, -0.33333333f);
            hp = __builtin_fmaf(a2, hp, 1.0f);
            float t = a * hp;
            float g = (t - 1.0f) * 28.853901f;
            float p = __builtin_amdgcn_exp2f(g);
            int diff = dql - (nt*16 + r);
            p = ((unsigned)diff <= 512u) ? p : 0.f;
            ps += p;
            union{float f; unsigned int u;} cv; cv.f = p;
            w2[rr] = cv.u + 0x8000u;
          }
          pk[j] = (w2[0] >> 16) | (w2[1] & 0xffff0000u);
        }
        const int row = lr;                      // q-row within wave
        const int bytecol = nt*32 + lg*8;        // key*2
        const int c16 = bytecol >> 4;
        char* basep = (char*)Pw + row*128 + (((c16 ^ (row & 7)) << 4)) + (bytecol & 15);
        *(unsigned int*)(basep)     = pk[0];
        *(unsigned int*)(basep + 4) = pk[1];
      }
      lst += ps;
    }

    __builtin_amdgcn_s_waitcnt(0xC07F);     // lgkmcnt(0): this wave's P writes done
    __builtin_amdgcn_sched_barrier(0);

    // PV: o[q][d] += P[q][key] * Vt[d][key]
    #pragma unroll
    for (int kk = 0; kk < 2; ++kk){
      bf16x8 pa = *(const bf16x8*)((char*)Pw + lr*128 + (((kk*4+lg) ^ (lr & 7)) << 4));
      #pragma unroll
      for (int dt = 0; dt < 8; ++dt){
        int vrow = dt*16 + lr;
        bf16x8 vf = *(const bf16x8*)&Vs[vrow*64 + (((kk*4 + lg) ^ (vrow & 7)))*8];
        o[dt] = MFMA16(pa, vf, o[dt]);
      }
    }
  }

  // finalize: sum l across lg groups, normalize, store
  lst += __shfl_xor(lst, 16);
  lst += __shfl_xor(lst, 32);
  {
    float l = __shfl(lst, lg*4 + (0));  // placeholder to keep lst live
    (void)l;
  }
  #pragma unroll
  for (int r = 0; r < 4; ++r){
    float l = __shfl(lst, lg*4 + r);    // sum for q-row lg*4+r
    float inv = 1.0f / l;
    int qg = qw + lg*4 + r;
    u16* op = ob + (size_t)(b*4096 + qg)*2048 + h*128;
    #pragma unroll
    for (int dt = 0; dt < 8; ++dt)
      op[dt*16 + lr] = f2bf(o[dt][r] * inv);
  }
}

// ---------------- launch ----------------
extern "C" void kernel_launch(void* const* d_in, const int* in_sizes, int n_in,
                              void* d_out, int out_size, void* d_ws, size_t ws_size,
                              hipStream_t stream)
{
  const float* x  = (const float*)d_in[0];
  const float* wq = (const float*)d_in[1];
  const float* wk = (const float*)d_in[2];
  const float* wv = (const float*)d_in[3];
  const float* wo = (const float*)d_in[4];
  float* outp = (float*)d_out;
  char* ws = (char*)d_ws;

  u16* xb    = (u16*)(ws);                  // bf16 x; reused as attn out
  u16* ob    = xb;
  u16* qbuf  = (u16*)(ws + 33554432u);
  u16* kbuf  = (u16*)(ws + 67108864u);
  u16* vtb   = (u16*)(ws + 75497472u);
  u16* wqkvb = (u16*)(ws + 83886080u);
  u16* wob   = (u16*)(ws + 96468992u);
  float* ct  = (float*)(ws + 104857600u);
  float* st  = (float*)(ws + 105906176u);

  k_convert<<<2048, 256, 0, stream>>>(x,  xb,            4194304);
  k_convert<<<2048, 256, 0, stream>>>(wq, wqkvb,         1048576);
  k_convert<<<1024, 256, 0, stream>>>(wk, wqkvb+4194304,  262144);
  k_convert<<<1024, 256, 0, stream>>>(wv, wqkvb+5242880,  262144);
  k_convert<<<2048, 256, 0, stream>>>(wo, wob,           1048576);
  k_rope_table<<<1024, 256, 0, stream>>>(ct, st);

  dim3 g1(8192/128, 3072/128);
  k_gemm_bt<1><<<g1, 256, 0, stream>>>(xb, wqkvb, nullptr, qbuf, kbuf, vtb, 8192, 3072, 2048);

  k_rope_apply<<<2048, 256, 0, stream>>>(qbuf, ct, st, 256, 8192*256);
  k_rope_apply<<<2048, 256, 0, stream>>>(kbuf, ct, st, 64,  8192*64);

  k_attn<<<1024, 512, 0, stream>>>(qbuf, kbuf, vtb, ob);

  dim3 g2(8192/128, 2048/128);
  k_gemm_bt<0><<<g2, 256, 0, stream>>>(ob, wob, outp, nullptr, nullptr, nullptr, 8192, 2048, 2048);
}

// Round 5
// 418.835 us; speedup vs baseline: 1.4105x; 1.0498x over previous
//
#include <hip/hip_runtime.h>
#include <stdint.h>
#include <stddef.h>

typedef float f32x4 __attribute__((ext_vector_type(4)));
typedef short bf16x8 __attribute__((ext_vector_type(8)));
typedef unsigned short u16;
typedef u16 u16x4 __attribute__((ext_vector_type(4)));
typedef u16 u16x8 __attribute__((ext_vector_type(8)));

#define MFMA16(a,b,c) __builtin_amdgcn_mfma_f32_16x16x32_bf16((a),(b),(c),0,0,0)

__device__ __forceinline__ float bf2f(u16 u){ union{unsigned int i;float f;}v; v.i=((unsigned int)u)<<16; return v.f; }
__device__ __forceinline__ u16 f2bf(float f){ union{float f;unsigned int i;}v; v.f=f; unsigned int x=v.i; return (u16)((x + 0x7FFFu + ((x>>16)&1u))>>16); }

__device__ __forceinline__ void gload_lds16(const void* g, void* l){
  __builtin_amdgcn_global_load_lds((const __attribute__((address_space(1))) void*)g,
                                   (__attribute__((address_space(3))) void*)l, 16, 0, 0);
}

// raw barrier with compiler memory fence (no vmcnt drain — that's the point)
#define BARRIER() do{ __builtin_amdgcn_sched_barrier(0); asm volatile("" ::: "memory"); \
  __builtin_amdgcn_s_barrier(); __builtin_amdgcn_sched_barrier(0); }while(0)

// ---------------- elementwise ----------------
__global__ void k_convert(const float* __restrict__ src, u16* __restrict__ dst, int n4){
  int stride = gridDim.x * blockDim.x;
  for (int i = blockIdx.x*blockDim.x + threadIdx.x; i < n4; i += stride){
    float4 v = ((const float4*)src)[i];
    u16x4 o; o[0]=f2bf(v.x); o[1]=f2bf(v.y); o[2]=f2bf(v.z); o[3]=f2bf(v.w);
    ((u16x4*)dst)[i] = o;
  }
}

__global__ void k_rope_table(float* __restrict__ ct, float* __restrict__ st){
  int i = blockIdx.x*blockDim.x + threadIdx.x; // 4096*64 exactly
  int s = i >> 6, p = i & 63;
  float freq = 1.0f / powf(10000.0f, (float)(2*p) * (1.0f/128.0f));
  float ang = (float)s * freq;
  ct[i] = cosf(ang); st[i] = sinf(ang);
}

// in-place RoPE on bf16 [rows x cols], cols8 = cols/8, position = row % 4096
__global__ void k_rope_apply(u16* __restrict__ t, const float* __restrict__ ct,
                             const float* __restrict__ st, int cols8, int n){
  int stride = gridDim.x * blockDim.x;
  for (int i = blockIdx.x*blockDim.x + threadIdx.x; i < n; i += stride){
    int row = i / cols8, rem = i - row*cols8;
    int s = row & 4095;
    int d0 = (rem*8) & 127;
    int p0 = d0 >> 1;
    const float4 c  = *(const float4*)(ct + s*64 + p0);
    const float4 sn = *(const float4*)(st + s*64 + p0);
    u16x8 v = ((const u16x8*)t)[i];
    u16x8 o;
    float x1, x2;
    x1=bf2f(v[0]); x2=bf2f(v[1]); o[0]=f2bf(x1*c.x-x2*sn.x); o[1]=f2bf(x1*sn.x+x2*c.x);
    x1=bf2f(v[2]); x2=bf2f(v[3]); o[2]=f2bf(x1*c.y-x2*sn.y); o[3]=f2bf(x1*sn.y+x2*c.y);
    x1=bf2f(v[4]); x2=bf2f(v[5]); o[4]=f2bf(x1*c.z-x2*sn.z); o[5]=f2bf(x1*sn.z+x2*c.z);
    x1=bf2f(v[6]); x2=bf2f(v[7]); o[6]=f2bf(x1*c.w-x2*sn.w); o[7]=f2bf(x1*sn.w+x2*c.w);
    ((u16x8*)t)[i] = o;
  }
}

// ---------------- 256x256 8-phase GEMM: C[M,N] = A[M,K] @ Bt[N,K]^T ----------------
// 8 waves (2M x 4N), BK=64, 128KiB dynamic LDS double-buffer, counted vmcnt(4),
// raw barriers, setprio around MFMA clusters. Stage schedule is fully
// barrier-ordered: B-halves of tile t+1 staged in ph1 of t (their last read was
// ph4 of t-1); A-halves of tile t+2 staged in ph4 of t (last A read was ph3 of t).
#define STAGE_OP(Gp, goff, Sp, half)                                              \
  gload_lds16((Gp) + (goff) + (size_t)(half)*hstep,                 (Sp) + (half)*8192 + dst0); \
  gload_lds16((Gp) + (goff) + (size_t)(half)*hstep + (size_t)8*K,   (Sp) + (half)*8192 + dst1);

template<int EPI>
__global__ __launch_bounds__(512, 2) void k_gemm256(
    const u16* __restrict__ A, const u16* __restrict__ Bt,
    float* __restrict__ Cf,
    u16* __restrict__ qb, u16* __restrict__ kb, u16* __restrict__ vtb,
    int M, int N, int K)
{
  extern __shared__ u16 Sdyn[];   // [2 dbuf][2 op][256 rows * 64 cols] bf16
  const int tid = threadIdx.x, wid = tid >> 6, lane = tid & 63;
  const int lr = lane & 15, lg = lane >> 4;
  const int wm = wid >> 2, wn = wid & 3;
  const int bm = blockIdx.x * 256, bn = blockIdx.y * 256;
  const int ns = K >> 6;
  const size_t hstep = (size_t)128 * K;

  // staging geometry: row&7 == lane>>3 for every chunk -> swizzled col is constant
  const int csw  = ((lane & 7) ^ (lane >> 3)) * 8;            // u16 units
  const size_t aoff = (size_t)(bm + wid*16 + (lane>>3)) * K + csw;
  const size_t boff = (size_t)(bn + wid*16 + (lane>>3)) * K + csw;
  const int dst0 = (wid*16)*64 + lane*8;                      // linear LDS dest (u16)
  const int dst1 = dst0 + 8*64;

  // ds_read fragment geometry (swizzle unit ^= row&7, row&7 == lr&7)
  const int rA = wm*128 + lr;
  const int rB = wn*64 + lr;
  const int u0 = ((0 + lg) ^ (lr & 7)) * 8;   // kk=0 units 0..3
  const int u1 = ((4 + lg) ^ (lr & 7)) * 8;   // kk=1 units 4..7

  f32x4 acc[8][4] = {};

  // ---- prologue: stage tile0 (A+B) and tile1 (A); drain once ----
  {
    u16* SA0 = Sdyn;
    u16* SB0 = Sdyn + 16384;
    u16* SA1 = Sdyn + 2*16384;
    STAGE_OP(A,  aoff, SA0, 0); STAGE_OP(A,  aoff, SA0, 1);
    STAGE_OP(Bt, boff, SB0, 0); STAGE_OP(Bt, boff, SB0, 1);
    const size_t k1p = (size_t)((1 <= ns-1) ? 1 : ns-1) << 6;
    STAGE_OP(A,  aoff + k1p, SA1, 0); STAGE_OP(A,  aoff + k1p, SA1, 1);
    asm volatile("s_waitcnt vmcnt(0)" ::: "memory");
    BARRIER();
  }

  bf16x8 af[8], bq0, bq1;

  for (int t = 0; t < ns; ++t){
    const int buf = t & 1;
    u16* SA  = Sdyn + (buf*2 + 0)*16384;
    u16* SB  = Sdyn + (buf*2 + 1)*16384;
    u16* SBn = Sdyn + ((buf^1)*2 + 1)*16384;
    const int t1 = (t+1 <= ns-1) ? t+1 : ns-1;
    const int t2 = (t+2 <= ns-1) ? t+2 : ns-1;
    const size_t k1 = (size_t)t1 << 6, k2 = (size_t)t2 << 6;

    // ---- phase 1: read A[kk0] + B[n0,n1][kk0]; stage (t+1) B0,B1 ----
    #pragma unroll
    for (int m = 0; m < 8; ++m) af[m] = *(const bf16x8*)(SA + (rA + m*16)*64 + u0);
    bq0 = *(const bf16x8*)(SB + (rB +  0)*64 + u0);
    bq1 = *(const bf16x8*)(SB + (rB + 16)*64 + u0);
    STAGE_OP(Bt, boff + k1, SBn, 0);
    STAGE_OP(Bt, boff + k1, SBn, 1);
    BARRIER();
    __builtin_amdgcn_s_setprio(1);
    #pragma unroll
    for (int m = 0; m < 8; ++m){
      acc[m][0] = MFMA16(af[m], bq0, acc[m][0]);
      acc[m][1] = MFMA16(af[m], bq1, acc[m][1]);
    }
    __builtin_amdgcn_s_setprio(0);
    BARRIER();

    // ---- phase 2: read B[n2,n3][kk0] ----
    bq0 = *(const bf16x8*)(SB + (rB + 32)*64 + u0);
    bq1 = *(const bf16x8*)(SB + (rB + 48)*64 + u0);
    BARRIER();
    __builtin_amdgcn_s_setprio(1);
    #pragma unroll
    for (int m = 0; m < 8; ++m){
      acc[m][2] = MFMA16(af[m], bq0, acc[m][2]);
      acc[m][3] = MFMA16(af[m], bq1, acc[m][3]);
    }
    __builtin_amdgcn_s_setprio(0);
    BARRIER();

    // ---- phase 3: read A[kk1] + B[n0,n1][kk1] ----
    #pragma unroll
    for (int m = 0; m < 8; ++m) af[m] = *(const bf16x8*)(SA + (rA + m*16)*64 + u1);
    bq0 = *(const bf16x8*)(SB + (rB +  0)*64 + u1);
    bq1 = *(const bf16x8*)(SB + (rB + 16)*64 + u1);
    BARRIER();
    __builtin_amdgcn_s_setprio(1);
    #pragma unroll
    for (int m = 0; m < 8; ++m){
      acc[m][0] = MFMA16(af[m], bq0, acc[m][0]);
      acc[m][1] = MFMA16(af[m], bq1, acc[m][1]);
    }
    __builtin_amdgcn_s_setprio(0);
    BARRIER();

    // ---- phase 4: read B[n2,n3][kk1]; stage (t+2) A0,A1; counted vmcnt ----
    bq0 = *(const bf16x8*)(SB + (rB + 32)*64 + u1);
    bq1 = *(const bf16x8*)(SB + (rB + 48)*64 + u1);
    STAGE_OP(A, aoff + k2, SA, 0);
    STAGE_OP(A, aoff + k2, SA, 1);
    asm volatile("s_waitcnt vmcnt(4)" ::: "memory");   // (t+2)A in flight; tile t+1 landed
    BARRIER();
    __builtin_amdgcn_s_setprio(1);
    #pragma unroll
    for (int m = 0; m < 8; ++m){
      acc[m][2] = MFMA16(af[m], bq0, acc[m][2]);
      acc[m][3] = MFMA16(af[m], bq1, acc[m][3]);
    }
    __builtin_amdgcn_s_setprio(0);
    BARRIER();
  }

  // ---- epilogue ----
  #pragma unroll
  for (int m = 0; m < 8; ++m){
    int mrow = bm + wm*128 + m*16 + lg*4;
    #pragma unroll
    for (int n = 0; n < 4; ++n){
      int ncol = bn + wn*64 + n*16 + lr;
      f32x4 v = acc[m][n];
      if (EPI == 0){
        #pragma unroll
        for (int r = 0; r < 4; ++r)
          Cf[(size_t)(mrow + r)*N + ncol] = v[r];
      } else {
        if (ncol < 2048){                     // Q: (B*S, 2048)
          #pragma unroll
          for (int r = 0; r < 4; ++r) qb[(size_t)(mrow + r)*2048 + ncol] = f2bf(v[r]);
        } else if (ncol < 2560){              // K: (B*S, 512)
          #pragma unroll
          for (int r = 0; r < 4; ++r) kb[(size_t)(mrow + r)*512 + (ncol - 2048)] = f2bf(v[r]);
        } else {                              // V transposed: ((b*4+hk)*128+d, 4096)
          int np = ncol - 2560, hkk = np >> 7, d = np & 127;
          int bb2 = mrow >> 12, sl = mrow & 4095;
          u16x4 pk;
          #pragma unroll
          for (int r = 0; r < 4; ++r) pk[r] = f2bf(v[r]);
          *(u16x4*)(vtb + ((size_t)((bb2*4 + hkk)*128 + d))*4096 + sl) = pk;
        }
      }
    }
  }
}

// ---------------- attention: 8 waves x 16 q-rows = 128 rows/block ----------------
__global__ __launch_bounds__(512, 4) void k_attn(
    const u16* __restrict__ qb, const u16* __restrict__ kb,
    const u16* __restrict__ vtb, u16* __restrict__ ob)
{
  __shared__ u16 Ks[64*128];    // [key 64][dim 128], 16B-chunk XOR(row&7) swizzle
  __shared__ u16 Vs[128*64];    // [dim 128][key 64], 16B-chunk XOR(row&7) swizzle
  __shared__ u16 Ps[8][16*64];  // per-wave P: [qrow 16][key 64], XOR(row&7) swizzle

  const int bid0 = blockIdx.x;
  const int bid = (bid0 & 7)*128 + (bid0 >> 3);     // bijective XCD swizzle (1024 = 8*128)
  const int qblk = bid & 31, h = (bid >> 5) & 15, b = bid >> 9;
  const int hk = h >> 2;
  const int tid = threadIdx.x, wid = tid >> 6, lane = tid & 63;
  const int lr = lane & 15, lg = lane >> 4;
  const int q0 = qblk*128;
  const int qw = q0 + wid*16;

  bf16x8 qf[4];
  {
    const u16* qp = qb + (size_t)(b*4096 + qw + lr)*2048 + h*128;
    #pragma unroll
    for (int ks = 0; ks < 4; ++ks)
      qf[ks] = *(const bf16x8*)(qp + ks*32 + lg*8);
  }

  const int sA = wid*64 + lane;
  const int krA = sA >> 4, kcA = sA & 15;
  const int krB = krA + 32;
  const int vrA = sA >> 3, vcA = sA & 7;
  const int vrB = vrA + 64;
  const u16* kSrcA = kb + (size_t)(b*4096 + krA)*512 + hk*128 + ((kcA ^ (krA & 7))*8);
  const u16* kSrcB = kb + (size_t)(b*4096 + krB)*512 + hk*128 + ((kcA ^ (krB & 7))*8);
  const u16* vSrcA = vtb + ((size_t)(b*4 + hk)*128 + vrA)*4096 + ((vcA ^ (vrA & 7))*8);
  const u16* vSrcB = vtb + ((size_t)(b*4 + hk)*128 + vrB)*4096 + ((vcA ^ (vrB & 7))*8);
  u16* const ldsKA = Ks + sA*8;
  u16* const ldsKB = Ks + (sA + 512)*8;
  u16* const ldsVA = Vs + sA*8;
  u16* const ldsVB = Vs + (sA + 512)*8;

  u16* Pw = (u16*)Ps[wid];

  f32x4 o[8] = {};
  float lst = 0.f;

  const int kt0 = (q0 >= 512) ? (q0 - 512) : 0;
  const int ktend = q0 + 128;

  for (int kt = kt0; kt < ktend; kt += 64){
    __syncthreads();
    gload_lds16(kSrcA + (size_t)kt*512, ldsKA);
    gload_lds16(kSrcB + (size_t)kt*512, ldsKB);
    gload_lds16(vSrcA + kt, ldsVA);
    gload_lds16(vSrcB + kt, ldsVB);
    __syncthreads();

    if (kt > qw + 15 || kt + 63 < qw - 512) continue;

    f32x4 sc[4] = {};
    #pragma unroll
    for (int ks = 0; ks < 4; ++ks){
      #pragma unroll
      for (int nt = 0; nt < 4; ++nt){
        int krow = nt*16 + lr;
        bf16x8 kf = *(const bf16x8*)&Ks[krow*128 + (((ks*4 + lg) ^ (krow & 7)))*8];
        sc[nt] = MFMA16(kf, qf[ks], sc[nt]);
      }
    }

    {
      int dql = (qw + lr) - kt - lg*4;
      float ps = 0.f;
      #pragma unroll
      for (int nt = 0; nt < 4; ++nt){
        unsigned int pk[2];
        #pragma unroll
        for (int j = 0; j < 2; ++j){
          unsigned int w2[2];
          #pragma unroll
          for (int rr = 0; rr < 2; ++rr){
            const int r = j*2 + rr;
            float a = sc[nt][r] * 0.00441941738f;
            a = fminf(fmaxf(a, -0.55f), 0.55f);
            float a2 = a*a;
            float hp = __builtin_fmaf(a2, 0.13333333f, -0.33333333f);
            hp = __builtin_fmaf(a2, hp, 1.0f);
            float t = a * hp;
            float g = (t - 1.0f) * 28.853901f;
            float p = __builtin_amdgcn_exp2f(g);
            int diff = dql - (nt*16 + r);
            p = ((unsigned)diff <= 512u) ? p : 0.f;
            ps += p;
            union{float f; unsigned int u;} cv; cv.f = p;
            w2[rr] = cv.u + 0x8000u;
          }
          pk[j] = (w2[0] >> 16) | (w2[1] & 0xffff0000u);
        }
        const int row = lr;
        const int bytecol = nt*32 + lg*8;
        const int c16 = bytecol >> 4;
        char* basep = (char*)Pw + row*128 + (((c16 ^ (row & 7)) << 4)) + (bytecol & 15);
        *(unsigned int*)(basep)     = pk[0];
        *(unsigned int*)(basep + 4) = pk[1];
      }
      lst += ps;
    }

    __builtin_amdgcn_s_waitcnt(0xC07F);
    __builtin_amdgcn_sched_barrier(0);

    #pragma unroll
    for (int kk = 0; kk < 2; ++kk){
      bf16x8 pa = *(const bf16x8*)((char*)Pw + lr*128 + (((kk*4+lg) ^ (lr & 7)) << 4));
      #pragma unroll
      for (int dt = 0; dt < 8; ++dt){
        int vrow = dt*16 + lr;
        bf16x8 vf = *(const bf16x8*)&Vs[vrow*64 + (((kk*4 + lg) ^ (vrow & 7)))*8];
        o[dt] = MFMA16(pa, vf, o[dt]);
      }
    }
  }

  lst += __shfl_xor(lst, 16);
  lst += __shfl_xor(lst, 32);
  #pragma unroll
  for (int r = 0; r < 4; ++r){
    float l = __shfl(lst, lg*4 + r);
    float inv = 1.0f / l;
    int qg = qw + lg*4 + r;
    u16* op = ob + (size_t)(b*4096 + qg)*2048 + h*128;
    #pragma unroll
    for (int dt = 0; dt < 8; ++dt)
      op[dt*16 + lr] = f2bf(o[dt][r] * inv);
  }
}

// ---------------- launch ----------------
extern "C" void kernel_launch(void* const* d_in, const int* in_sizes, int n_in,
                              void* d_out, int out_size, void* d_ws, size_t ws_size,
                              hipStream_t stream)
{
  const float* x  = (const float*)d_in[0];
  const float* wq = (const float*)d_in[1];
  const float* wk = (const float*)d_in[2];
  const float* wv = (const float*)d_in[3];
  const float* wo = (const float*)d_in[4];
  float* outp = (float*)d_out;
  char* ws = (char*)d_ws;

  u16* xb    = (u16*)(ws);                  // bf16 x; reused as attn out
  u16* ob    = xb;
  u16* qbuf  = (u16*)(ws + 33554432u);
  u16* kbuf  = (u16*)(ws + 67108864u);
  u16* vtb   = (u16*)(ws + 75497472u);
  u16* wqkvb = (u16*)(ws + 83886080u);
  u16* wob   = (u16*)(ws + 96468992u);
  float* ct  = (float*)(ws + 104857600u);
  float* st  = (float*)(ws + 105906176u);

  hipFuncSetAttribute(reinterpret_cast<const void*>(&k_gemm256<1>),
                      hipFuncAttributeMaxDynamicSharedMemorySize, 131072);
  hipFuncSetAttribute(reinterpret_cast<const void*>(&k_gemm256<0>),
                      hipFuncAttributeMaxDynamicSharedMemorySize, 131072);

  k_convert<<<2048, 256, 0, stream>>>(x,  xb,            4194304);
  k_convert<<<2048, 256, 0, stream>>>(wq, wqkvb,         1048576);
  k_convert<<<1024, 256, 0, stream>>>(wk, wqkvb+4194304,  262144);
  k_convert<<<1024, 256, 0, stream>>>(wv, wqkvb+5242880,  262144);
  k_convert<<<2048, 256, 0, stream>>>(wo, wob,           1048576);
  k_rope_table<<<1024, 256, 0, stream>>>(ct, st);

  dim3 g1(8192/256, 3072/256);
  k_gemm256<1><<<g1, 512, 131072, stream>>>(xb, wqkvb, nullptr, qbuf, kbuf, vtb, 8192, 3072, 2048);

  k_rope_apply<<<2048, 256, 0, stream>>>(qbuf, ct, st, 256, 8192*256);
  k_rope_apply<<<2048, 256, 0, stream>>>(kbuf, ct, st, 64,  8192*64);

  k_attn<<<1024, 512, 0, stream>>>(qbuf, kbuf, vtb, ob);

  dim3 g2(8192/256, 2048/256);
  k_gemm256<0><<<g2, 512, 131072, stream>>>(ob, wob, outp, nullptr, nullptr, nullptr, 8192, 2048, 2048);
}